// Round 3
// baseline (324.370 us; speedup 1.0000x reference)
//
#include <hip/hip_runtime.h>

typedef __attribute__((ext_vector_type(8))) short bf16x8;
typedef __attribute__((ext_vector_type(8))) unsigned short u16x8;
typedef __attribute__((ext_vector_type(4))) float f32x4;

__device__ __forceinline__ unsigned short f2bf(float f) {
    unsigned int u = __float_as_uint(f);
    u += 0x7fffu + ((u >> 16) & 1u);   // RNE
    return (unsigned short)(u >> 16);
}

// ---------------- Kernel 1: row-normalize fp32 -> bf16 ----------------
// One wave per row (D=512 floats: 8 floats/lane = two float4 loads).
__global__ __launch_bounds__(256) void normalize_rows(
    const float* __restrict__ X, unsigned short* __restrict__ Y) {
    const int wave = threadIdx.x >> 6;
    const int lane = threadIdx.x & 63;
    const long row = (long)blockIdx.x * 4 + wave;

    const float4* xr = (const float4*)(X + row * 512);
    float4 a = xr[lane * 2];
    float4 b = xr[lane * 2 + 1];

    float s = a.x * a.x + a.y * a.y + a.z * a.z + a.w * a.w
            + b.x * b.x + b.y * b.y + b.z * b.z + b.w * b.w;
#pragma unroll
    for (int off = 32; off; off >>= 1) s += __shfl_xor(s, off, 64);

    const float inv = rsqrtf(s);   // norm ~22.6; eps=1e-8 never binds

    u16x8 o;
    o[0] = f2bf(a.x * inv); o[1] = f2bf(a.y * inv);
    o[2] = f2bf(a.z * inv); o[3] = f2bf(a.w * inv);
    o[4] = f2bf(b.x * inv); o[5] = f2bf(b.y * inv);
    o[6] = f2bf(b.z * inv); o[7] = f2bf(b.w * inv);
    ((u16x8*)(Y + row * 512))[lane] = o;
}

// ---------------- Kernel 2: C = 1 - Y*Y^T, bf16 MFMA, fp32 out ----------------
// 128x128 tile, BK=32, 4 waves in 2x2, each wave 64x64 as 4x4 of 16x16x32.
#define GLDS16(g, l)                                                         \
    __builtin_amdgcn_global_load_lds(                                        \
        (const __attribute__((address_space(1))) void*)(g),                  \
        (__attribute__((address_space(3))) void*)(l), 16, 0, 0)

__global__ __launch_bounds__(256) void cosdist_gemm(
    const unsigned short* __restrict__ Y, float* __restrict__ out) {
    constexpr int N = 8192, K = 512, BM = 128, BK = 32;

    __shared__ __align__(16) short As[BM * BK];
    __shared__ __align__(16) short Bs[BM * BK];

    const int tid  = threadIdx.x;
    const int lane = tid & 63;
    const int wave = tid >> 6;
    const int wr = wave >> 1, wc = wave & 1;
    const int bm = blockIdx.x * BM;
    const int bn = blockIdx.y * BM;

    f32x4 acc[4][4] = {};

    // staging: 512 chunks of 16B per tile; thread handles chunks tid, tid+256
    const int c0 = tid, c1 = tid + 256;
    const unsigned short* Ag0 = Y + (size_t)(bm + (c0 >> 2)) * K + ((c0 & 3) << 3);
    const unsigned short* Ag1 = Y + (size_t)(bm + (c1 >> 2)) * K + ((c1 & 3) << 3);
    const unsigned short* Bg0 = Y + (size_t)(bn + (c0 >> 2)) * K + ((c0 & 3) << 3);
    const unsigned short* Bg1 = Y + (size_t)(bn + (c1 >> 2)) * K + ((c1 & 3) << 3);
    short* Al0 = As + c0 * 8;
    short* Al1 = As + c1 * 8;
    short* Bl0 = Bs + c0 * 8;
    short* Bl1 = Bs + c1 * 8;

    // fragment addresses: A[m=lane&15][k=(lane>>4)*8+j], row-major stride BK
    const int frow = lane & 15;
    const int fk   = (lane >> 4) << 3;

    for (int k0 = 0; k0 < K; k0 += BK) {
        GLDS16(Ag0 + k0, Al0);
        GLDS16(Ag1 + k0, Al1);
        GLDS16(Bg0 + k0, Bl0);
        GLDS16(Bg1 + k0, Bl1);
        __syncthreads();   // compiler drains vmcnt before s_barrier

        bf16x8 af[4], bfr[4];
#pragma unroll
        for (int t = 0; t < 4; ++t) {
            af[t]  = *(const bf16x8*)&As[(wr * 64 + t * 16 + frow) * BK + fk];
            bfr[t] = *(const bf16x8*)&Bs[(wc * 64 + t * 16 + frow) * BK + fk];
        }
#pragma unroll
        for (int mt = 0; mt < 4; ++mt)
#pragma unroll
            for (int nt = 0; nt < 4; ++nt)
                acc[mt][nt] = __builtin_amdgcn_mfma_f32_16x16x32_bf16(
                    af[mt], bfr[nt], acc[mt][nt], 0, 0, 0);
        __syncthreads();
    }

    // epilogue: C/D map col=lane&15, row=(lane>>4)*4+reg (symmetric C: swap-safe)
    const int crow0 = wr * 64 + ((lane >> 4) << 2);
    const int ccol0 = wc * 64 + (lane & 15);
#pragma unroll
    for (int mt = 0; mt < 4; ++mt)
#pragma unroll
        for (int nt = 0; nt < 4; ++nt)
#pragma unroll
            for (int r = 0; r < 4; ++r) {
                const int row = bm + crow0 + mt * 16 + r;
                const int col = bn + ccol0 + nt * 16;
                out[(size_t)row * N + col] = 1.0f - acc[mt][nt][r];
            }
}

extern "C" void kernel_launch(void* const* d_in, const int* in_sizes, int n_in,
                              void* d_out, int out_size, void* d_ws, size_t ws_size,
                              hipStream_t stream) {
    const float* X = (const float*)d_in[0];          // fp32 [N,512]
    float* out = (float*)d_out;                      // fp32 [N,N]
    unsigned short* Y = (unsigned short*)d_ws;       // bf16 [N,512] scratch

    const int D = 512;
    const int N = in_sizes[0] / D;   // 8192

    normalize_rows<<<N / 4, 256, 0, stream>>>(X, Y);
    dim3 grid(N / 128, N / 128);
    cosdist_gemm<<<grid, 256, 0, stream>>>(Y, out);
}